// Round 15
// baseline (998.760 us; speedup 1.0000x reference)
//
#include <hip/hip_runtime.h>
#include <hip/hip_bf16.h>

#define DEV __device__ __forceinline__

typedef unsigned short u16;
typedef __attribute__((ext_vector_type(8))) short bf16x8;
typedef __attribute__((ext_vector_type(4))) float f32x4;

static constexpr int MB_ = 2;
static constexpr int T_  = 1024;
static constexpr int H_  = 1024;
static constexpr int NH_ = 16;
static constexpr int L_  = 6;
static constexpr int V_  = 8192;
static constexpr int FF_ = 4096;
static constexpr int M_  = MB_ * T_;   // 2048 token rows
static constexpr int QKVN = 3 * H_;

DEV u16 f2bf(float x) {
  __hip_bfloat16 h = __float2bfloat16(x);
  return *reinterpret_cast<u16*>(&h);
}
DEV float bf2f(u16 v) {
  unsigned u = (unsigned)v << 16;
  float f;
  __builtin_memcpy(&f, &u, 4);
  return f;
}

// ---------------- transpose: 128x128 per block, double-buffered subtiles ------
// Ts[2][64][65] (33 KB): load both column-subtiles (8 float4 in flight),
// one barrier, store both, one barrier -> 4 barriers/block vs 8.
DEV void transpose_tile128s(float (*Ts)[64][65], const float* __restrict__ W,
                            u16* __restrict__ WT, int R, int C, int bx, int by)
{
  const int t = threadIdx.x;
  const int lr = t >> 4;             // 0..15
  const int lcq = (t & 15) * 4;      // 0..60
  #pragma unroll
  for (int si = 0; si < 2; ++si) {
    const int r0 = by * 128 + si * 64;
    #pragma unroll
    for (int sj = 0; sj < 2; ++sj) {
      const int c0 = bx * 128 + sj * 64;
      #pragma unroll
      for (int it = 0; it < 4; ++it) {
        int r = it * 16 + lr;
        float4 v = *(const float4*)(W + (size_t)(r0 + r) * C + c0 + lcq);
        Ts[sj][r][lcq + 0] = v.x; Ts[sj][r][lcq + 1] = v.y;
        Ts[sj][r][lcq + 2] = v.z; Ts[sj][r][lcq + 3] = v.w;
      }
    }
    __syncthreads();
    #pragma unroll
    for (int sj = 0; sj < 2; ++sj) {
      const int c0 = bx * 128 + sj * 64;
      #pragma unroll
      for (int it = 0; it < 4; ++it) {
        int n = it * 16 + lr;
        ushort4 u = make_ushort4(f2bf(Ts[sj][lcq + 0][n]), f2bf(Ts[sj][lcq + 1][n]),
                                 f2bf(Ts[sj][lcq + 2][n]), f2bf(Ts[sj][lcq + 3][n]));
        *(ushort4*)(WT + (size_t)(c0 + n) * R + r0 + lcq) = u;
      }
    }
    __syncthreads();
  }
}

// 768 ids: Wq,Wk,Wv,Wo (4x64) + W1 (256) + W2 (256)
DEV void transpose_layer_body(float (*Ts)[64][65], int t,
    const float* Wq, const float* Wk, const float* Wv, const float* Wo,
    const float* W1, const float* W2,
    u16* qkvT, u16* oT, u16* w1T, u16* w2T)
{
  if (t < 256) {
    int m = t >> 6, idx = t & 63, bx = idx & 7, by = idx >> 3;
    const float* W = (m == 0) ? Wq : (m == 1) ? Wk : (m == 2) ? Wv : Wo;
    u16* WT = (m == 3) ? oT : qkvT + (size_t)m * H_ * H_;
    transpose_tile128s(Ts, W, WT, H_, H_, bx, by);
  } else if (t < 512) {
    int idx = t - 256;
    transpose_tile128s(Ts, W1, w1T, H_, FF_, idx & 31, idx >> 5);
  } else {
    int idx = t - 512;
    transpose_tile128s(Ts, W2, w2T, FF_, H_, idx & 7, idx >> 3);
  }
}

// ---------------- embedding + qkv-bias concat + layer-0 transpose (fused) -----
// Transposes dispatch FIRST (latency-bound, narrow), embed last (wide tail).
__global__ __launch_bounds__(256) void embed_concat_kernel(
    const int* __restrict__ x, const float* __restrict__ tok,
    const float* __restrict__ pos, float* __restrict__ h, u16* __restrict__ hb,
    const float* __restrict__ bq, const float* __restrict__ bk,
    const float* __restrict__ bv, float* __restrict__ outb,
    const float* Wq0, const float* Wk0, const float* Wv0, const float* Wo0,
    const float* W10, const float* W20,
    u16* qkvT, u16* oT, u16* w1T0, u16* w2T0)
{
  __shared__ float Ts[2][64][65];
  int i = blockIdx.x;
  if (i < 768) {
    transpose_layer_body(Ts, i, Wq0, Wk0, Wv0, Wo0, W10, W20,
                         qkvT, oT, w1T0, w2T0);
  } else if (i < 768 + M_) {
    int row = i - 768;
    int t = threadIdx.x;
    int id = x[row];
    int tt = row & (T_ - 1);
    float4 a = *(const float4*)(tok + (size_t)id * H_ + t * 4);
    float4 b = *(const float4*)(pos + (size_t)tt * H_ + t * 4);
    float4 r = make_float4(a.x + b.x, a.y + b.y, a.z + b.z, a.w + b.w);
    *(float4*)(h + (size_t)row * H_ + t * 4) = r;
    ushort4 u = make_ushort4(f2bf(r.x), f2bf(r.y), f2bf(r.z), f2bf(r.w));
    *(ushort4*)(hb + (size_t)row * H_ + t * 4) = u;
  } else {
    int l = i - 768 - M_;
    for (int j = threadIdx.x; j < H_; j += 256) {
      outb[(size_t)l * QKVN + j]          = bq[(size_t)l * H_ + j];
      outb[(size_t)l * QKVN + H_ + j]     = bk[(size_t)l * H_ + j];
      outb[(size_t)l * QKVN + 2 * H_ + j] = bv[(size_t)l * H_ + j];
    }
  }
}

// ---------------- pipelined GEMM body (r8/r12-exact schedule) ----------------
// 4-buffer, BK=32, counted vmcnt, STG-early, 2 blocks/CU.
// 2-row-packed conflict-free LDS layout (r8-verified: SQ_LDS_BANK_CONFLICT=0).

#define GLOAD_LDS16(g, l)                                              \
  __builtin_amdgcn_global_load_lds(                                    \
      (const __attribute__((address_space(1))) void*)(g),              \
      (__attribute__((address_space(3))) void*)(l), 16, 0, 0)

DEV void stage_t(const u16* __restrict__ G, int ldk, int r0g, int kofs,
                 u16* lds, int w, int lane)
{
  const int rl = ((lane >> 3) << 1) | ((lane >> 2) & 1);  // logical row in 16-group
  #pragma unroll
  for (int j = 0; j < 2; ++j) {
    const int row0 = w * 32 + j * 16;
    const int row = row0 + rl;
    const int c = (lane & 3) ^ (((row0 >> 1) + (lane >> 3)) & 3);
    const u16* g = G + (size_t)(r0g + row) * ldk + kofs + c * 8;
    GLOAD_LDS16(g, lds + row0 * 32);        // wave-uniform base, lane*16B auto
  }
}

DEV bf16x8 frag3(const u16* lds, int rr, int ch) {
  return *(const bf16x8*)(lds + (rr >> 1) * 64 + (rr & 1) * 32 +
                          ((ch ^ ((rr >> 1) & 3)) * 8));
}

template<int N>
DEV void wait_vm_barrier() {
  asm volatile("s_waitcnt vmcnt(%0)" :: "n"(N) : "memory");
  __builtin_amdgcn_s_barrier();
}

DEV void comp3(const u16* As, const u16* Bs, f32x4 (&acc)[4][4],
               int wr, int wc, int lc, int lg)
{
  bf16x8 af[4], bv[4];
  #pragma unroll
  for (int mi = 0; mi < 4; ++mi)
    af[mi] = frag3(As, wr * 64 + mi * 16 + lc, lg);
  #pragma unroll
  for (int ni = 0; ni < 4; ++ni)
    bv[ni] = frag3(Bs, wc * 64 + ni * 16 + lc, lg);
  #pragma unroll
  for (int mi = 0; mi < 4; ++mi)
    #pragma unroll
    for (int ni = 0; ni < 4; ++ni)
      acc[mi][ni] = __builtin_amdgcn_mfma_f32_16x16x32_bf16(af[mi], bv[ni], acc[mi][ni], 0, 0, 0);
}

template<bool PARTIAL, bool DO_GELU, bool WF, bool WB>
DEV void gemm_body(u16* SMEM,
    const u16* __restrict__ A, const u16* __restrict__ BT,
    const float* __restrict__ bias, float* __restrict__ Cf,
    u16* __restrict__ Cb, u16* __restrict__ Pb,
    int N, int K, int Ksub, int lid, int nwgx, int nwgy, int zid)
{
  const int tid = threadIdx.x;
  const int lane = tid & 63, w = tid >> 6;
  const int wr = w >> 1, wc = w & 1;
  const int lc = lane & 15, lg = lane >> 4;

  // bijective XCD swizzle, m FASTEST within an XCD (B-panel reuse per XCD)
  const int nwg = nwgx * nwgy;
  const int q8 = nwg >> 3, r8s = nwg & 7;
  const int xcd = lid & 7, ord = lid >> 3;
  const int sid = (xcd < r8s ? xcd * (q8 + 1) : r8s * (q8 + 1) + (xcd - r8s) * q8) + ord;
  const int m0 = (sid % nwgy) * 128, n0 = (sid / nwgy) * 128;

  const int kb = zid * Ksub;
  const int NT = Ksub >> 5;

  f32x4 acc[4][4];
  #pragma unroll
  for (int i = 0; i < 4; ++i)
    #pragma unroll
    for (int j = 0; j < 4; ++j) {
      f32x4 z = {0.f, 0.f, 0.f, 0.f};
      acc[i][j] = z;
    }

  auto STG = [&](int t, int b) {
    stage_t(A,  K, m0, kb + t * 32, SMEM + b * 4096, w, lane);
    stage_t(BT, K, n0, kb + t * 32, SMEM + 16384 + b * 4096, w, lane);
  };

  STG(0, 0);
  STG(1, 1);
  int t = 0;
  for (; t < NT - 2; ++t) {
    STG(t + 2, (t + 2) & 3);
    wait_vm_barrier<8>();     // stage(t) complete; t+1,t+2 stay in flight
    comp3(SMEM + (t & 3) * 4096, SMEM + 16384 + (t & 3) * 4096, acc, wr, wc, lc, lg);
  }
  wait_vm_barrier<4>();       // stage(NT-2) complete
  comp3(SMEM + (t & 3) * 4096, SMEM + 16384 + (t & 3) * 4096, acc, wr, wc, lc, lg);
  ++t;
  wait_vm_barrier<0>();       // stage(NT-1) complete
  comp3(SMEM + (t & 3) * 4096, SMEM + 16384 + (t & 3) * 4096, acc, wr, wc, lc, lg);

  const size_t zofs = (size_t)zid * M_ * N;
  #pragma unroll
  for (int mi = 0; mi < 4; ++mi) {
    #pragma unroll
    for (int ni = 0; ni < 4; ++ni) {
      int gn = n0 + wc * 64 + ni * 16 + lc;
      float bvv = PARTIAL ? 0.f : bias[gn];
      #pragma unroll
      for (int r = 0; r < 4; ++r) {
        int gm = m0 + wr * 64 + mi * 16 + lg * 4 + r;
        float v = acc[mi][ni][r];
        if (PARTIAL) {
          Pb[zofs + (size_t)gm * N + gn] = f2bf(v);   // bf16 partials
        } else {
          v += bvv;
          if (DO_GELU) v = 0.5f * v * (1.f + erff(v * 0.70710678118654752f));
          if (WF) Cf[(size_t)gm * N + gn] = v;
          if (WB) Cb[(size_t)gm * N + gn] = f2bf(v);
        }
      }
    }
  }
}

template<bool PARTIAL, bool DO_GELU, bool WF, bool WB>
__global__ __launch_bounds__(256, 2) void gemm3(
    const u16* __restrict__ A, const u16* __restrict__ BT,
    const float* __restrict__ bias, float* __restrict__ Cf,
    u16* __restrict__ Cb, u16* __restrict__ Pb, int N, int K, int Ksub)
{
  __shared__ __align__(16) u16 SMEM[32768];
  gemm_body<PARTIAL, DO_GELU, WF, WB>(SMEM, A, BT, bias, Cf, Cb, Pb, N, K, Ksub,
      blockIdx.y * gridDim.x + blockIdx.x, gridDim.x, gridDim.y, blockIdx.z);
}

// transposes FIRST (narrow latency-bound), W1 GEMM last (wide tail).
__global__ __launch_bounds__(256, 2) void gemmW1_fused(
    const u16* __restrict__ A, const u16* __restrict__ w1T,
    const float* __restrict__ bias, u16* __restrict__ m1,
    const float* nWq, const float* nWk, const float* nWv, const float* nWo,
    const float* nW1, const float* nW2,
    u16* nqkvT, u16* noT, u16* nw1T, u16* nw2T,
    const float* hW, u16* hT)
{
  __shared__ __align__(16) u16 SMEM[32768];
  const int id = blockIdx.x;
  const int ntr = nWq ? 768 : 512;
  if (id < ntr) {
    float (*Ts)[64][65] = (float(*)[64][65])SMEM;   // 33 KB of the 64 KB union
    if (nWq) {
      transpose_layer_body(Ts, id, nWq, nWk, nWv, nWo, nW1, nW2,
                           nqkvT, noT, nw1T, nw2T);
    } else {
      transpose_tile128s(Ts, hW, hT, H_, V_, id & 63, id >> 6);  // 512 head tiles
    }
  } else {
    gemm_body<false, true, false, true>(SMEM, A, w1T, bias, nullptr, m1, nullptr,
                                        FF_, H_, H_, id - ntr, 32, 16, 0);
  }
}

// ---------------- split-K reduce (bf16 partials) + bias + residual + LN -------
__global__ __launch_bounds__(256) void ln2_kernel(
    const u16* __restrict__ Pb, int S,
    const float* __restrict__ bias,
    const float* __restrict__ g, const float* __restrict__ be,
    const float* __restrict__ gf, const float* __restrict__ bef,
    float* __restrict__ h, u16* __restrict__ hb)
{
  __shared__ float red[8];
  int row = blockIdx.x, t = threadIdx.x;
  int lane = t & 63, w = t >> 6;
  float4 v = *(const float4*)(h + (size_t)row * H_ + t * 4);
  float4 bb = *(const float4*)(bias + t * 4);
  v.x += bb.x; v.y += bb.y; v.z += bb.z; v.w += bb.w;
  for (int s0 = 0; s0 < S; ++s0) {
    ushort4 p = *(const ushort4*)(Pb + (size_t)s0 * M_ * H_ + (size_t)row * H_ + t * 4);
    v.x += bf2f(p.x); v.y += bf2f(p.y); v.z += bf2f(p.z); v.w += bf2f(p.w);
  }
  float s = v.x + v.y + v.z + v.w;
  float q = v.x * v.x + v.y * v.y + v.z * v.z + v.w * v.w;
  #pragma unroll
  for (int o = 1; o < 64; o <<= 1) { s += __shfl_xor(s, o); q += __shfl_xor(q, o); }
  if (lane == 0) { red[w] = s; red[4 + w] = q; }
  __syncthreads();
  float S1 = red[0] + red[1] + red[2] + red[3];
  float Q1 = red[4] + red[5] + red[6] + red[7];
  float mu  = S1 * (1.f / H_);
  float var = Q1 * (1.f / H_) - mu * mu;
  float inv = rsqrtf(var + 1e-5f);
  float4 gv = *(const float4*)(g  + t * 4);
  float4 bv = *(const float4*)(be + t * 4);
  float o0 = (v.x - mu) * inv * gv.x + bv.x;
  float o1 = (v.y - mu) * inv * gv.y + bv.y;
  float o2 = (v.z - mu) * inv * gv.z + bv.z;
  float o3 = (v.w - mu) * inv * gv.w + bv.w;
  if (gf == nullptr) {
    *(float4*)(h + (size_t)row * H_ + t * 4) = make_float4(o0, o1, o2, o3);
    ushort4 u = make_ushort4(f2bf(o0), f2bf(o1), f2bf(o2), f2bf(o3));
    *(ushort4*)(hb + (size_t)row * H_ + t * 4) = u;
  } else {
    float s2 = o0 + o1 + o2 + o3;
    float q2 = o0 * o0 + o1 * o1 + o2 * o2 + o3 * o3;
    #pragma unroll
    for (int o = 1; o < 64; o <<= 1) { s2 += __shfl_xor(s2, o); q2 += __shfl_xor(q2, o); }
    __syncthreads();
    if (lane == 0) { red[w] = s2; red[4 + w] = q2; }
    __syncthreads();
    float S2 = red[0] + red[1] + red[2] + red[3];
    float Q2 = red[4] + red[5] + red[6] + red[7];
    float mu2  = S2 * (1.f / H_);
    float var2 = Q2 * (1.f / H_) - mu2 * mu2;
    float inv2 = rsqrtf(var2 + 1e-5f);
    float4 gv2 = *(const float4*)(gf  + t * 4);
    float4 bv2 = *(const float4*)(bef + t * 4);
    ushort4 u = make_ushort4(f2bf((o0 - mu2) * inv2 * gv2.x + bv2.x),
                             f2bf((o1 - mu2) * inv2 * gv2.y + bv2.y),
                             f2bf((o2 - mu2) * inv2 * gv2.z + bv2.z),
                             f2bf((o3 - mu2) * inv2 * gv2.w + bv2.w));
    *(ushort4*)(hb + (size_t)row * H_ + t * 4) = u;
  }
}

// ---------------- flash attention (causal), QBLK=128, 8 waves ----------------
__global__ __launch_bounds__(512) void attn_kernel(
    const u16* __restrict__ qkv, u16* __restrict__ Og)
{
  __shared__ __align__(16) u16 Ks[2][64][72];
  __shared__ __align__(16) u16 Vs[2][64][72];      // transposed: [d][key]
  __shared__ __align__(16) u16 QPs[8][16][72];     // Q stage (prologue) / P bounce

  const int qb = gridDim.x - 1 - blockIdx.x;       // long blocks first
  const int bh = blockIdx.y;
  const int b = bh >> 4, hh = bh & 15;
  const int q0 = qb * 128;
  const size_t base  = ((size_t)b * T_) * QKVN + (size_t)hh * 64;
  const size_t baseO = ((size_t)b * T_) * H_ + (size_t)hh * 64;

  const int tid = threadIdx.x;
  const int lane = tid & 63, w = tid >> 6;         // 8 waves
  const int lc = lane & 15, lg = lane >> 4;

  const int rk = tid >> 3, dk = (tid & 7) << 3;    // K: 64 rows x 8 chunks
  const int vk = tid & 63, vd = (tid >> 6) << 3;   // V: 64 rows x 8 d-chunks
  const int rq = tid >> 2, cq = (tid & 3) << 4;    // Q: 128 rows x 2 chunks

  bf16x8 kr, vr;
  kr = *(const bf16x8*)(qkv + base + H_ + (size_t)rk * QKVN + dk);
  vr = *(const bf16x8*)(qkv + base + 2 * H_ + (size_t)vk * QKVN + vd);
  *(bf16x8*)&QPs[rq >> 4][rq & 15][cq] =
      *(const bf16x8*)(qkv + base + (size_t)(q0 + rq) * QKVN + cq);
  *(bf16x8*)&QPs[rq >> 4][rq & 15][cq + 8] =
      *(const bf16x8*)(qkv + base + (size_t)(q0 + rq) * QKVN + cq + 8);
  *(bf16x8*)&Ks[0][rk][dk] = kr;
  #pragma unroll
  for (int j = 0; j < 8; ++j) Vs[0][vd + j][vk] = ((const u16*)&vr)[j];
  __syncthreads();
  bf16x8 aq0 = *(const bf16x8*)&QPs[w][lc][lg * 8];
  bf16x8 aq1 = *(const bf16x8*)&QPs[w][lc][32 + lg * 8];

  float m_r[4], l_r[4];
  f32x4 oa[4];
  #pragma unroll
  for (int i = 0; i < 4; ++i) {
    m_r[i] = -1e30f; l_r[i] = 0.f;
    f32x4 z = {0.f, 0.f, 0.f, 0.f};
    oa[i] = z;
  }
  const float sc2 = 0.125f * 1.4426950408889634f;
  const int NT = 2 * qb + 2;
  const int rmin = q0 + w * 16;                    // wave's first q-row

  for (int kv = 0; kv < NT; ++kv) {
    const int cur = kv & 1, nxt = cur ^ 1;
    if (kv + 1 < NT) {
      kr = *(const bf16x8*)(qkv + base + H_ + (size_t)((kv + 1) * 64 + rk) * QKVN + dk);
      vr = *(const bf16x8*)(qkv + base + 2 * H_ + (size_t)((kv + 1) * 64 + vk) * QKVN + vd);
    }

    const bool live = (kv * 64 <= rmin + 15);      // else tile fully masked
    if (live) {
      const bool partial = (kv * 64 + 63 > rmin);
      f32x4 sfr[4];
      #pragma unroll
      for (int ni = 0; ni < 4; ++ni) { f32x4 z = {0.f,0.f,0.f,0.f}; sfr[ni] = z; }
      __builtin_amdgcn_s_setprio(1);
      #pragma unroll
      for (int ni = 0; ni < 4; ++ni) {
        bf16x8 bk0 = *(const bf16x8*)&Ks[cur][ni * 16 + lc][lg * 8];
        bf16x8 bk1 = *(const bf16x8*)&Ks[cur][ni * 16 + lc][32 + lg * 8];
        sfr[ni] = __builtin_amdgcn_mfma_f32_16x16x32_bf16(aq0, bk0, sfr[ni], 0, 0, 0);
        sfr[ni] = __builtin_amdgcn_mfma_f32_16x16x32_bf16(aq1, bk1, sfr[ni], 0, 0, 0);
      }
      __builtin_amdgcn_s_setprio(0);
      if (partial) {
        #pragma unroll
        for (int ni = 0; ni < 4; ++ni)
          #pragma unroll
          for (int r = 0; r < 4; ++r)
            if (kv * 64 + ni * 16 + lc > rmin + lg * 4 + r) sfr[ni][r] = -1e30f;
      }
      #pragma unroll
      for (int r = 0; r < 4; ++r) {
        float pm = fmaxf(fmaxf(sfr[0][r], sfr[1][r]), fmaxf(sfr[2][r], sfr[3][r]));
        pm = fmaxf(pm, __shfl_xor(pm, 1));
        pm = fmaxf(pm, __shfl_xor(pm, 2));
        pm = fmaxf(pm, __shfl_xor(pm, 4));
        pm = fmaxf(pm, __shfl_xor(pm, 8));
        float mn = fmaxf(m_r[r], pm);
        float al = exp2f(sc2 * (m_r[r] - mn));
        m_r[r] = mn; l_r[r] *= al;
        #pragma unroll
        for (int f = 0; f < 4; ++f) oa[f][r] *= al;
        float rs = 0.f;
        #pragma unroll
        for (int ni = 0; ni < 4; ++ni) {
          float p = exp2f(sc2 * (sfr[ni][r] - mn));
          sfr[ni][r] = p; rs += p;
        }
        rs += __shfl_xor(rs, 1); rs += __shfl_xor(rs, 2);
        rs += __shfl_xor(rs, 4); rs += __shfl_xor(rs, 8);
        l_r[r] += rs;
      }
      #pragma unroll
      for (int ni = 0; ni < 4; ++ni)
        #pragma unroll
        for (int r = 0; r < 4; ++r)
          QPs[w][lg * 4 + r][ni * 16 + lc] = f2bf(sfr[ni][r]);
      bf16x8 ap0 = *(const bf16x8*)&QPs[w][lc][lg * 8];
      bf16x8 ap1 = *(const bf16x8*)&QPs[w][lc][32 + lg * 8];
      __builtin_amdgcn_s_setprio(1);
      #pragma unroll
      for (int f = 0; f < 4; ++f) {
        bf16x8 bv0 = *(const bf16x8*)&Vs[cur][f * 16 + lc][lg * 8];
        bf16x8 bv1 = *(const bf16x8*)&Vs[cur][f * 16 + lc][32 + lg * 8];
        oa[f] = __builtin_amdgcn_mfma_f32_16x16x32_bf16(ap0, bv0, oa[f], 0, 0, 0);
        oa[f] = __builtin_amdgcn_mfma_f32_16x16x32_bf16(ap1, bv1, oa[f], 0, 0, 0);
      }
      __builtin_amdgcn_s_setprio(0);
    }

    if (kv + 1 < NT) {
      *(bf16x8*)&Ks[nxt][rk][dk] = kr;
      #pragma unroll
      for (int j = 0; j < 8; ++j) Vs[nxt][vd + j][vk] = ((const u16*)&vr)[j];
      __syncthreads();
    }
  }

  #pragma unroll
  for (int r = 0; r < 4; ++r) {
    float inv = 1.f / l_r[r];
    int grow = q0 + w * 16 + lg * 4 + r;
    #pragma unroll
    for (int f = 0; f < 4; ++f)
      Og[baseO + (size_t)grow * H_ + f * 16 + lc] = f2bf(oa[f][r] * inv);
  }
}

// ---------------- host ----------------
extern "C" void kernel_launch(void* const* d_in, const int* in_sizes, int n_in,
                              void* d_out, int out_size, void* d_ws, size_t ws_size,
                              hipStream_t stream)
{
  const int*   x    = (const int*)  d_in[0];
  const float* tok  = (const float*)d_in[1];
  const float* pos  = (const float*)d_in[2];
  const float* Wq   = (const float*)d_in[3];
  const float* bq   = (const float*)d_in[4];
  const float* Wk   = (const float*)d_in[5];
  const float* bk   = (const float*)d_in[6];
  const float* Wv   = (const float*)d_in[7];
  const float* bv   = (const float*)d_in[8];
  const float* Wo   = (const float*)d_in[9];
  const float* bo   = (const float*)d_in[10];
  const float* W1   = (const float*)d_in[11];
  const float* b1   = (const float*)d_in[12];
  const float* W2   = (const float*)d_in[13];
  const float* b2   = (const float*)d_in[14];
  const float* g1   = (const float*)d_in[15];
  const float* be1  = (const float*)d_in[16];
  const float* g2   = (const float*)d_in[17];
  const float* be2  = (const float*)d_in[18];
  const float* gf   = (const float*)d_in[19];
  const float* bef  = (const float*)d_in[20];
  const float* hW   = (const float*)d_in[21];
  const float* hbias= (const float*)d_in[22];
  float* out = (float*)d_out;

  char* wsp = (char*)d_ws;
  size_t off = 0;
  auto alloc = [&](size_t bytes) -> void* {
    void* p = wsp + off;
    off += (bytes + 255) & ~(size_t)255;
    return p;
  };
  float* h    = (float*)alloc((size_t)M_ * H_ * 4);
  u16*   hb   = (u16*)  alloc((size_t)M_ * H_ * 2);
  u16*   qkv  = (u16*)  alloc((size_t)M_ * QKVN * 2);
  u16*   ob_  = (u16*)  alloc((size_t)M_ * H_ * 2);
  u16*   m1   = (u16*)  alloc((size_t)M_ * FF_ * 2);
  u16*   Pb   = (u16*)  alloc((size_t)4 * M_ * H_ * 2);   // bf16 split-K partials
  u16*   hT   = (u16*)  alloc((size_t)V_ * H_ * 2);
  u16*   qkvT = (u16*)  alloc((size_t)QKVN * H_ * 2);
  u16*   oT   = (u16*)  alloc((size_t)H_ * H_ * 2);
  u16*   w1Tb = (u16*)  alloc((size_t)2 * H_ * FF_ * 2);  // double-buffered
  u16*   w2Tb = (u16*)  alloc((size_t)2 * FF_ * H_ * 2);  // double-buffered
  float* bqkv = (float*)alloc((size_t)L_ * QKVN * 4);
  (void)in_sizes; (void)n_in; (void)out_size; (void)ws_size;

  auto w1T = [&](int l) { return w1Tb + (size_t)(l & 1) * H_ * FF_; };
  auto w2T = [&](int l) { return w2Tb + (size_t)(l & 1) * FF_ * H_; };

  // transposes(l0) first, then embed rows, then bias concat
  embed_concat_kernel<<<768 + M_ + L_, 256, 0, stream>>>(
      x, tok, pos, h, hb, bq, bk, bv, bqkv,
      Wq, Wk, Wv, Wo, W1, W2, qkvT, oT, w1T(0), w2T(0));

  for (int l = 0; l < L_; ++l) {
    // QKV: [2048,3072]
    gemm3<false, false, false, true><<<dim3(QKVN / 128, M_ / 128, 1), 256, 0, stream>>>(
        hb, qkvT, bqkv + (size_t)l * QKVN, nullptr, qkv, nullptr, QKVN, H_, H_);
    attn_kernel<<<dim3(T_ / 128, MB_ * NH_), 512, 0, stream>>>(qkv, ob_);
    // O-proj: split-K x4 -> 512 blocks, bf16 partials
    gemm3<true, false, false, false><<<dim3(H_ / 128, M_ / 128, 4), 256, 0, stream>>>(
        ob_, oT, nullptr, nullptr, nullptr, Pb, H_, H_, H_ / 4);
    ln2_kernel<<<M_, 256, 0, stream>>>(Pb, 4, bo + l * H_, g1 + l * H_, be1 + l * H_,
                                       nullptr, nullptr, h, hb);
    // transposes(l+1 or head) first, W1+GELU last
    if (l + 1 < L_) {
      int nl = l + 1;
      gemmW1_fused<<<768 + 512, 256, 0, stream>>>(
          hb, w1T(l), b1 + (size_t)l * FF_, m1,
          Wq + (size_t)nl * H_ * H_, Wk + (size_t)nl * H_ * H_,
          Wv + (size_t)nl * H_ * H_, Wo + (size_t)nl * H_ * H_,
          W1 + (size_t)nl * H_ * FF_, W2 + (size_t)nl * FF_ * H_,
          qkvT, oT, w1T(nl), w2T(nl), nullptr, nullptr);
    } else {
      gemmW1_fused<<<512 + 512, 256, 0, stream>>>(
          hb, w1T(l), b1 + (size_t)l * FF_, m1,
          nullptr, nullptr, nullptr, nullptr, nullptr, nullptr,
          nullptr, nullptr, nullptr, nullptr, hW, hT);
    }
    // W2: split-K x4 -> bf16 partials
    gemm3<true, false, false, false><<<dim3(H_ / 128, M_ / 128, 4), 256, 0, stream>>>(
        m1, w2T(l), nullptr, nullptr, nullptr, Pb, H_, FF_, FF_ / 4);
    if (l + 1 < L_) {
      ln2_kernel<<<M_, 256, 0, stream>>>(Pb, 4, b2 + l * H_, g2 + l * H_, be2 + l * H_,
                                         nullptr, nullptr, h, hb);
    } else {
      ln2_kernel<<<M_, 256, 0, stream>>>(Pb, 4, b2 + l * H_, g2 + l * H_, be2 + l * H_,
                                         gf, bef, h, hb);
    }
  }

  gemm3<false, false, true, false><<<dim3(V_ / 128, M_ / 128, 1), 256, 0, stream>>>(
      hb, hT, hbias, out, nullptr, nullptr, V_, H_, H_);
}

// Round 16
// 979.536 us; speedup vs baseline: 1.0196x; 1.0196x over previous
//
#include <hip/hip_runtime.h>
#include <hip/hip_bf16.h>

#define DEV __device__ __forceinline__

typedef unsigned short u16;
typedef __attribute__((ext_vector_type(8))) short bf16x8;
typedef __attribute__((ext_vector_type(4))) float f32x4;

static constexpr int MB_ = 2;
static constexpr int T_  = 1024;
static constexpr int H_  = 1024;
static constexpr int NH_ = 16;
static constexpr int L_  = 6;
static constexpr int V_  = 8192;
static constexpr int FF_ = 4096;
static constexpr int M_  = MB_ * T_;   // 2048 token rows
static constexpr int QKVN = 3 * H_;

DEV u16 f2bf(float x) {
  __hip_bfloat16 h = __float2bfloat16(x);
  return *reinterpret_cast<u16*>(&h);
}
DEV float bf2f(u16 v) {
  unsigned u = (unsigned)v << 16;
  float f;
  __builtin_memcpy(&f, &u, 4);
  return f;
}

// ---------------- transpose: 128x128 per block, double-buffered subtiles ------
DEV void transpose_tile128s(float (*Ts)[64][65], const float* __restrict__ W,
                            u16* __restrict__ WT, int R, int C, int bx, int by)
{
  const int t = threadIdx.x;
  const int lr = t >> 4;             // 0..15
  const int lcq = (t & 15) * 4;      // 0..60
  #pragma unroll
  for (int si = 0; si < 2; ++si) {
    const int r0 = by * 128 + si * 64;
    #pragma unroll
    for (int sj = 0; sj < 2; ++sj) {
      const int c0 = bx * 128 + sj * 64;
      #pragma unroll
      for (int it = 0; it < 4; ++it) {
        int r = it * 16 + lr;
        float4 v = *(const float4*)(W + (size_t)(r0 + r) * C + c0 + lcq);
        Ts[sj][r][lcq + 0] = v.x; Ts[sj][r][lcq + 1] = v.y;
        Ts[sj][r][lcq + 2] = v.z; Ts[sj][r][lcq + 3] = v.w;
      }
    }
    __syncthreads();
    #pragma unroll
    for (int sj = 0; sj < 2; ++sj) {
      const int c0 = bx * 128 + sj * 64;
      #pragma unroll
      for (int it = 0; it < 4; ++it) {
        int n = it * 16 + lr;
        ushort4 u = make_ushort4(f2bf(Ts[sj][lcq + 0][n]), f2bf(Ts[sj][lcq + 1][n]),
                                 f2bf(Ts[sj][lcq + 2][n]), f2bf(Ts[sj][lcq + 3][n]));
        *(ushort4*)(WT + (size_t)(c0 + n) * R + r0 + lcq) = u;
      }
    }
    __syncthreads();
  }
}

// 768 ids: Wq,Wk,Wv,Wo (4x64) + W1 (256) + W2 (256)
DEV void transpose_layer_body(float (*Ts)[64][65], int t,
    const float* Wq, const float* Wk, const float* Wv, const float* Wo,
    const float* W1, const float* W2,
    u16* qkvT, u16* oT, u16* w1T, u16* w2T)
{
  if (t < 256) {
    int m = t >> 6, idx = t & 63, bx = idx & 7, by = idx >> 3;
    const float* W = (m == 0) ? Wq : (m == 1) ? Wk : (m == 2) ? Wv : Wo;
    u16* WT = (m == 3) ? oT : qkvT + (size_t)m * H_ * H_;
    transpose_tile128s(Ts, W, WT, H_, H_, bx, by);
  } else if (t < 512) {
    int idx = t - 256;
    transpose_tile128s(Ts, W1, w1T, H_, FF_, idx & 31, idx >> 5);
  } else {
    int idx = t - 512;
    transpose_tile128s(Ts, W2, w2T, FF_, H_, idx & 7, idx >> 3);
  }
}

// ---------------- embedding + qkv-bias concat + layer-0 transpose (fused) -----
__global__ __launch_bounds__(256) void embed_concat_kernel(
    const int* __restrict__ x, const float* __restrict__ tok,
    const float* __restrict__ pos, u16* __restrict__ hb,
    const float* __restrict__ bq, const float* __restrict__ bk,
    const float* __restrict__ bv, float* __restrict__ outb,
    const float* Wq0, const float* Wk0, const float* Wv0, const float* Wo0,
    const float* W10, const float* W20,
    u16* qkvT, u16* oT, u16* w1T0, u16* w2T0)
{
  __shared__ float Ts[2][64][65];
  int i = blockIdx.x;
  if (i < 768) {
    transpose_layer_body(Ts, i, Wq0, Wk0, Wv0, Wo0, W10, W20,
                         qkvT, oT, w1T0, w2T0);
  } else if (i < 768 + M_) {
    int row = i - 768;
    int t = threadIdx.x;
    int id = x[row];
    int tt = row & (T_ - 1);
    float4 a = *(const float4*)(tok + (size_t)id * H_ + t * 4);
    float4 b = *(const float4*)(pos + (size_t)tt * H_ + t * 4);
    ushort4 u = make_ushort4(f2bf(a.x + b.x), f2bf(a.y + b.y),
                             f2bf(a.z + b.z), f2bf(a.w + b.w));
    *(ushort4*)(hb + (size_t)row * H_ + t * 4) = u;
  } else {
    int l = i - 768 - M_;
    for (int j = threadIdx.x; j < H_; j += 256) {
      outb[(size_t)l * QKVN + j]          = bq[(size_t)l * H_ + j];
      outb[(size_t)l * QKVN + H_ + j]     = bk[(size_t)l * H_ + j];
      outb[(size_t)l * QKVN + 2 * H_ + j] = bv[(size_t)l * H_ + j];
    }
  }
}

// ---------------- pipelined GEMM body (r8/r12-exact schedule) ----------------
// 4-buffer, BK=32, counted vmcnt, STG-early, 2 blocks/CU.
// 2-row-packed conflict-free LDS layout (r8-verified: SQ_LDS_BANK_CONFLICT=0).

#define GLOAD_LDS16(g, l)                                              \
  __builtin_amdgcn_global_load_lds(                                    \
      (const __attribute__((address_space(1))) void*)(g),              \
      (__attribute__((address_space(3))) void*)(l), 16, 0, 0)

DEV void stage_t(const u16* __restrict__ G, int ldk, int r0g, int kofs,
                 u16* lds, int w, int lane)
{
  const int rl = ((lane >> 3) << 1) | ((lane >> 2) & 1);  // logical row in 16-group
  #pragma unroll
  for (int j = 0; j < 2; ++j) {
    const int row0 = w * 32 + j * 16;
    const int row = row0 + rl;
    const int c = (lane & 3) ^ (((row0 >> 1) + (lane >> 3)) & 3);
    const u16* g = G + (size_t)(r0g + row) * ldk + kofs + c * 8;
    GLOAD_LDS16(g, lds + row0 * 32);        // wave-uniform base, lane*16B auto
  }
}

DEV bf16x8 frag3(const u16* lds, int rr, int ch) {
  return *(const bf16x8*)(lds + (rr >> 1) * 64 + (rr & 1) * 32 +
                          ((ch ^ ((rr >> 1) & 3)) * 8));
}

template<int N>
DEV void wait_vm_barrier() {
  asm volatile("s_waitcnt vmcnt(%0)" :: "n"(N) : "memory");
  __builtin_amdgcn_s_barrier();
}

DEV void comp3(const u16* As, const u16* Bs, f32x4 (&acc)[4][4],
               int wr, int wc, int lc, int lg)
{
  bf16x8 af[4], bv[4];
  #pragma unroll
  for (int mi = 0; mi < 4; ++mi)
    af[mi] = frag3(As, wr * 64 + mi * 16 + lc, lg);
  #pragma unroll
  for (int ni = 0; ni < 4; ++ni)
    bv[ni] = frag3(Bs, wc * 64 + ni * 16 + lc, lg);
  #pragma unroll
  for (int mi = 0; mi < 4; ++mi)
    #pragma unroll
    for (int ni = 0; ni < 4; ++ni)
      acc[mi][ni] = __builtin_amdgcn_mfma_f32_16x16x32_bf16(af[mi], bv[ni], acc[mi][ni], 0, 0, 0);
}

template<bool PARTIAL, bool DO_GELU, bool WF, bool WB>
DEV void gemm_body(u16* SMEM,
    const u16* __restrict__ A, const u16* __restrict__ BT,
    const float* __restrict__ bias, float* __restrict__ Cf,
    u16* __restrict__ Cb, u16* __restrict__ Pb,
    int N, int K, int Ksub, int lid, int nwgx, int nwgy, int zid)
{
  const int tid = threadIdx.x;
  const int lane = tid & 63, w = tid >> 6;
  const int wr = w >> 1, wc = w & 1;
  const int lc = lane & 15, lg = lane >> 4;

  // bijective XCD swizzle, m FASTEST within an XCD (B-panel reuse per XCD)
  const int nwg = nwgx * nwgy;
  const int q8 = nwg >> 3, r8s = nwg & 7;
  const int xcd = lid & 7, ord = lid >> 3;
  const int sid = (xcd < r8s ? xcd * (q8 + 1) : r8s * (q8 + 1) + (xcd - r8s) * q8) + ord;
  const int m0 = (sid % nwgy) * 128, n0 = (sid / nwgy) * 128;

  const int kb = zid * Ksub;
  const int NT = Ksub >> 5;

  f32x4 acc[4][4];
  #pragma unroll
  for (int i = 0; i < 4; ++i)
    #pragma unroll
    for (int j = 0; j < 4; ++j) {
      f32x4 z = {0.f, 0.f, 0.f, 0.f};
      acc[i][j] = z;
    }

  auto STG = [&](int t, int b) {
    stage_t(A,  K, m0, kb + t * 32, SMEM + b * 4096, w, lane);
    stage_t(BT, K, n0, kb + t * 32, SMEM + 16384 + b * 4096, w, lane);
  };

  STG(0, 0);
  STG(1, 1);
  int t = 0;
  for (; t < NT - 2; ++t) {
    STG(t + 2, (t + 2) & 3);
    wait_vm_barrier<8>();     // stage(t) complete; t+1,t+2 stay in flight
    comp3(SMEM + (t & 3) * 4096, SMEM + 16384 + (t & 3) * 4096, acc, wr, wc, lc, lg);
  }
  wait_vm_barrier<4>();       // stage(NT-2) complete
  comp3(SMEM + (t & 3) * 4096, SMEM + 16384 + (t & 3) * 4096, acc, wr, wc, lc, lg);
  ++t;
  wait_vm_barrier<0>();       // stage(NT-1) complete
  comp3(SMEM + (t & 3) * 4096, SMEM + 16384 + (t & 3) * 4096, acc, wr, wc, lc, lg);

  const size_t zofs = (size_t)zid * M_ * N;
  #pragma unroll
  for (int mi = 0; mi < 4; ++mi) {
    #pragma unroll
    for (int ni = 0; ni < 4; ++ni) {
      int gn = n0 + wc * 64 + ni * 16 + lc;
      float bvv = PARTIAL ? 0.f : bias[gn];
      #pragma unroll
      for (int r = 0; r < 4; ++r) {
        int gm = m0 + wr * 64 + mi * 16 + lg * 4 + r;
        float v = acc[mi][ni][r];
        if (PARTIAL) {
          Pb[zofs + (size_t)gm * N + gn] = f2bf(v);   // bf16 partials
        } else {
          v += bvv;
          if (DO_GELU) v = 0.5f * v * (1.f + erff(v * 0.70710678118654752f));
          if (WF) Cf[(size_t)gm * N + gn] = v;
          if (WB) Cb[(size_t)gm * N + gn] = f2bf(v);
        }
      }
    }
  }
}

template<bool PARTIAL, bool DO_GELU, bool WF, bool WB>
__global__ __launch_bounds__(256, 2) void gemm3(
    const u16* __restrict__ A, const u16* __restrict__ BT,
    const float* __restrict__ bias, float* __restrict__ Cf,
    u16* __restrict__ Cb, u16* __restrict__ Pb, int N, int K, int Ksub)
{
  __shared__ __align__(16) u16 SMEM[32768];
  gemm_body<PARTIAL, DO_GELU, WF, WB>(SMEM, A, BT, bias, Cf, Cb, Pb, N, K, Ksub,
      blockIdx.y * gridDim.x + blockIdx.x, gridDim.x, gridDim.y, blockIdx.z);
}

// transposes FIRST (narrow latency-bound), W1 GEMM last (wide tail).
__global__ __launch_bounds__(256, 2) void gemmW1_fused(
    const u16* __restrict__ A, const u16* __restrict__ w1T,
    const float* __restrict__ bias, u16* __restrict__ m1,
    const float* nWq, const float* nWk, const float* nWv, const float* nWo,
    const float* nW1, const float* nW2,
    u16* nqkvT, u16* noT, u16* nw1T, u16* nw2T,
    const float* hW, u16* hT)
{
  __shared__ __align__(16) u16 SMEM[32768];
  const int id = blockIdx.x;
  const int ntr = nWq ? 768 : 512;
  if (id < ntr) {
    float (*Ts)[64][65] = (float(*)[64][65])SMEM;   // 33 KB of the 64 KB union
    if (nWq) {
      transpose_layer_body(Ts, id, nWq, nWk, nWv, nWo, nW1, nW2,
                           nqkvT, noT, nw1T, nw2T);
    } else {
      transpose_tile128s(Ts, hW, hT, H_, V_, id & 63, id >> 6);  // 512 head tiles
    }
  } else {
    gemm_body<false, true, false, true>(SMEM, A, w1T, bias, nullptr, m1, nullptr,
                                        FF_, H_, H_, id - ntr, 32, 16, 0);
  }
}

// ---------------- split-K reduce (bf16 partials) + bias + residual + LN -------
// Residual stream carried in hb (bf16): read hb, add bias+partials, LN,
// write hb. If gf != nullptr also applies the FINAL LayerNorm (second reduce).
__global__ __launch_bounds__(256) void ln2_kernel(
    const u16* __restrict__ Pb, int S,
    const float* __restrict__ bias,
    const float* __restrict__ g, const float* __restrict__ be,
    const float* __restrict__ gf, const float* __restrict__ bef,
    u16* __restrict__ hb)
{
  __shared__ float red[8];
  int row = blockIdx.x, t = threadIdx.x;
  int lane = t & 63, w = t >> 6;
  ushort4 hv = *(const ushort4*)(hb + (size_t)row * H_ + t * 4);
  float4 bb = *(const float4*)(bias + t * 4);
  float4 v = make_float4(bf2f(hv.x) + bb.x, bf2f(hv.y) + bb.y,
                         bf2f(hv.z) + bb.z, bf2f(hv.w) + bb.w);
  for (int s0 = 0; s0 < S; ++s0) {
    ushort4 p = *(const ushort4*)(Pb + (size_t)s0 * M_ * H_ + (size_t)row * H_ + t * 4);
    v.x += bf2f(p.x); v.y += bf2f(p.y); v.z += bf2f(p.z); v.w += bf2f(p.w);
  }
  float s = v.x + v.y + v.z + v.w;
  float q = v.x * v.x + v.y * v.y + v.z * v.z + v.w * v.w;
  #pragma unroll
  for (int o = 1; o < 64; o <<= 1) { s += __shfl_xor(s, o); q += __shfl_xor(q, o); }
  if (lane == 0) { red[w] = s; red[4 + w] = q; }
  __syncthreads();
  float S1 = red[0] + red[1] + red[2] + red[3];
  float Q1 = red[4] + red[5] + red[6] + red[7];
  float mu  = S1 * (1.f / H_);
  float var = Q1 * (1.f / H_) - mu * mu;
  float inv = rsqrtf(var + 1e-5f);
  float4 gv = *(const float4*)(g  + t * 4);
  float4 bv = *(const float4*)(be + t * 4);
  float o0 = (v.x - mu) * inv * gv.x + bv.x;
  float o1 = (v.y - mu) * inv * gv.y + bv.y;
  float o2 = (v.z - mu) * inv * gv.z + bv.z;
  float o3 = (v.w - mu) * inv * gv.w + bv.w;
  if (gf != nullptr) {
    float s2 = o0 + o1 + o2 + o3;
    float q2 = o0 * o0 + o1 * o1 + o2 * o2 + o3 * o3;
    #pragma unroll
    for (int o = 1; o < 64; o <<= 1) { s2 += __shfl_xor(s2, o); q2 += __shfl_xor(q2, o); }
    __syncthreads();                       // WAR on red
    if (lane == 0) { red[w] = s2; red[4 + w] = q2; }
    __syncthreads();
    float S2 = red[0] + red[1] + red[2] + red[3];
    float Q2 = red[4] + red[5] + red[6] + red[7];
    float mu2  = S2 * (1.f / H_);
    float var2 = Q2 * (1.f / H_) - mu2 * mu2;
    float inv2 = rsqrtf(var2 + 1e-5f);
    float4 gv2 = *(const float4*)(gf  + t * 4);
    float4 bv2 = *(const float4*)(bef + t * 4);
    o0 = (o0 - mu2) * inv2 * gv2.x + bv2.x;
    o1 = (o1 - mu2) * inv2 * gv2.y + bv2.y;
    o2 = (o2 - mu2) * inv2 * gv2.z + bv2.z;
    o3 = (o3 - mu2) * inv2 * gv2.w + bv2.w;
  }
  ushort4 u = make_ushort4(f2bf(o0), f2bf(o1), f2bf(o2), f2bf(o3));
  *(ushort4*)(hb + (size_t)row * H_ + t * 4) = u;
}

// ---------------- flash attention (causal), QBLK=128, 8 waves ----------------
__global__ __launch_bounds__(512) void attn_kernel(
    const u16* __restrict__ qkv, u16* __restrict__ Og)
{
  __shared__ __align__(16) u16 Ks[2][64][72];
  __shared__ __align__(16) u16 Vs[2][64][72];      // transposed: [d][key]
  __shared__ __align__(16) u16 QPs[8][16][72];     // Q stage (prologue) / P bounce

  const int qb = gridDim.x - 1 - blockIdx.x;       // long blocks first
  const int bh = blockIdx.y;
  const int b = bh >> 4, hh = bh & 15;
  const int q0 = qb * 128;
  const size_t base  = ((size_t)b * T_) * QKVN + (size_t)hh * 64;
  const size_t baseO = ((size_t)b * T_) * H_ + (size_t)hh * 64;

  const int tid = threadIdx.x;
  const int lane = tid & 63, w = tid >> 6;         // 8 waves
  const int lc = lane & 15, lg = lane >> 4;

  const int rk = tid >> 3, dk = (tid & 7) << 3;    // K: 64 rows x 8 chunks
  const int vk = tid & 63, vd = (tid >> 6) << 3;   // V: 64 rows x 8 d-chunks
  const int rq = tid >> 2, cq = (tid & 3) << 4;    // Q: 128 rows x 2 chunks

  bf16x8 kr, vr;
  kr = *(const bf16x8*)(qkv + base + H_ + (size_t)rk * QKVN + dk);
  vr = *(const bf16x8*)(qkv + base + 2 * H_ + (size_t)vk * QKVN + vd);
  *(bf16x8*)&QPs[rq >> 4][rq & 15][cq] =
      *(const bf16x8*)(qkv + base + (size_t)(q0 + rq) * QKVN + cq);
  *(bf16x8*)&QPs[rq >> 4][rq & 15][cq + 8] =
      *(const bf16x8*)(qkv + base + (size_t)(q0 + rq) * QKVN + cq + 8);
  *(bf16x8*)&Ks[0][rk][dk] = kr;
  #pragma unroll
  for (int j = 0; j < 8; ++j) Vs[0][vd + j][vk] = ((const u16*)&vr)[j];
  __syncthreads();
  bf16x8 aq0 = *(const bf16x8*)&QPs[w][lc][lg * 8];
  bf16x8 aq1 = *(const bf16x8*)&QPs[w][lc][32 + lg * 8];

  float m_r[4], l_r[4];
  f32x4 oa[4];
  #pragma unroll
  for (int i = 0; i < 4; ++i) {
    m_r[i] = -1e30f; l_r[i] = 0.f;
    f32x4 z = {0.f, 0.f, 0.f, 0.f};
    oa[i] = z;
  }
  const float sc2 = 0.125f * 1.4426950408889634f;
  const int NT = 2 * qb + 2;
  const int rmin = q0 + w * 16;                    // wave's first q-row

  for (int kv = 0; kv < NT; ++kv) {
    const int cur = kv & 1, nxt = cur ^ 1;
    if (kv + 1 < NT) {
      kr = *(const bf16x8*)(qkv + base + H_ + (size_t)((kv + 1) * 64 + rk) * QKVN + dk);
      vr = *(const bf16x8*)(qkv + base + 2 * H_ + (size_t)((kv + 1) * 64 + vk) * QKVN + vd);
    }

    const bool live = (kv * 64 <= rmin + 15);      // else tile fully masked
    if (live) {
      const bool partial = (kv * 64 + 63 > rmin);
      f32x4 sfr[4];
      #pragma unroll
      for (int ni = 0; ni < 4; ++ni) { f32x4 z = {0.f,0.f,0.f,0.f}; sfr[ni] = z; }
      __builtin_amdgcn_s_setprio(1);
      #pragma unroll
      for (int ni = 0; ni < 4; ++ni) {
        bf16x8 bk0 = *(const bf16x8*)&Ks[cur][ni * 16 + lc][lg * 8];
        bf16x8 bk1 = *(const bf16x8*)&Ks[cur][ni * 16 + lc][32 + lg * 8];
        sfr[ni] = __builtin_amdgcn_mfma_f32_16x16x32_bf16(aq0, bk0, sfr[ni], 0, 0, 0);
        sfr[ni] = __builtin_amdgcn_mfma_f32_16x16x32_bf16(aq1, bk1, sfr[ni], 0, 0, 0);
      }
      __builtin_amdgcn_s_setprio(0);
      if (partial) {
        #pragma unroll
        for (int ni = 0; ni < 4; ++ni)
          #pragma unroll
          for (int r = 0; r < 4; ++r)
            if (kv * 64 + ni * 16 + lc > rmin + lg * 4 + r) sfr[ni][r] = -1e30f;
      }
      #pragma unroll
      for (int r = 0; r < 4; ++r) {
        float pm = fmaxf(fmaxf(sfr[0][r], sfr[1][r]), fmaxf(sfr[2][r], sfr[3][r]));
        pm = fmaxf(pm, __shfl_xor(pm, 1));
        pm = fmaxf(pm, __shfl_xor(pm, 2));
        pm = fmaxf(pm, __shfl_xor(pm, 4));
        pm = fmaxf(pm, __shfl_xor(pm, 8));
        float mn = fmaxf(m_r[r], pm);
        float al = exp2f(sc2 * (m_r[r] - mn));
        m_r[r] = mn; l_r[r] *= al;
        #pragma unroll
        for (int f = 0; f < 4; ++f) oa[f][r] *= al;
        float rs = 0.f;
        #pragma unroll
        for (int ni = 0; ni < 4; ++ni) {
          float p = exp2f(sc2 * (sfr[ni][r] - mn));
          sfr[ni][r] = p; rs += p;
        }
        rs += __shfl_xor(rs, 1); rs += __shfl_xor(rs, 2);
        rs += __shfl_xor(rs, 4); rs += __shfl_xor(rs, 8);
        l_r[r] += rs;
      }
      #pragma unroll
      for (int ni = 0; ni < 4; ++ni)
        #pragma unroll
        for (int r = 0; r < 4; ++r)
          QPs[w][lg * 4 + r][ni * 16 + lc] = f2bf(sfr[ni][r]);
      bf16x8 ap0 = *(const bf16x8*)&QPs[w][lc][lg * 8];
      bf16x8 ap1 = *(const bf16x8*)&QPs[w][lc][32 + lg * 8];
      __builtin_amdgcn_s_setprio(1);
      #pragma unroll
      for (int f = 0; f < 4; ++f) {
        bf16x8 bv0 = *(const bf16x8*)&Vs[cur][f * 16 + lc][lg * 8];
        bf16x8 bv1 = *(const bf16x8*)&Vs[cur][f * 16 + lc][32 + lg * 8];
        oa[f] = __builtin_amdgcn_mfma_f32_16x16x32_bf16(ap0, bv0, oa[f], 0, 0, 0);
        oa[f] = __builtin_amdgcn_mfma_f32_16x16x32_bf16(ap1, bv1, oa[f], 0, 0, 0);
      }
      __builtin_amdgcn_s_setprio(0);
    }

    if (kv + 1 < NT) {
      *(bf16x8*)&Ks[nxt][rk][dk] = kr;
      #pragma unroll
      for (int j = 0; j < 8; ++j) Vs[nxt][vd + j][vk] = ((const u16*)&vr)[j];
      __syncthreads();
    }
  }

  #pragma unroll
  for (int r = 0; r < 4; ++r) {
    float inv = 1.f / l_r[r];
    int grow = q0 + w * 16 + lg * 4 + r;
    #pragma unroll
    for (int f = 0; f < 4; ++f)
      Og[baseO + (size_t)grow * H_ + f * 16 + lc] = f2bf(oa[f][r] * inv);
  }
}

// ---------------- host ----------------
extern "C" void kernel_launch(void* const* d_in, const int* in_sizes, int n_in,
                              void* d_out, int out_size, void* d_ws, size_t ws_size,
                              hipStream_t stream)
{
  const int*   x    = (const int*)  d_in[0];
  const float* tok  = (const float*)d_in[1];
  const float* pos  = (const float*)d_in[2];
  const float* Wq   = (const float*)d_in[3];
  const float* bq   = (const float*)d_in[4];
  const float* Wk   = (const float*)d_in[5];
  const float* bk   = (const float*)d_in[6];
  const float* Wv   = (const float*)d_in[7];
  const float* bv   = (const float*)d_in[8];
  const float* Wo   = (const float*)d_in[9];
  const float* bo   = (const float*)d_in[10];
  const float* W1   = (const float*)d_in[11];
  const float* b1   = (const float*)d_in[12];
  const float* W2   = (const float*)d_in[13];
  const float* b2   = (const float*)d_in[14];
  const float* g1   = (const float*)d_in[15];
  const float* be1  = (const float*)d_in[16];
  const float* g2   = (const float*)d_in[17];
  const float* be2  = (const float*)d_in[18];
  const float* gf   = (const float*)d_in[19];
  const float* bef  = (const float*)d_in[20];
  const float* hW   = (const float*)d_in[21];
  const float* hbias= (const float*)d_in[22];
  float* out = (float*)d_out;

  char* wsp = (char*)d_ws;
  size_t off = 0;
  auto alloc = [&](size_t bytes) -> void* {
    void* p = wsp + off;
    off += (bytes + 255) & ~(size_t)255;
    return p;
  };
  u16*   hb   = (u16*)  alloc((size_t)M_ * H_ * 2);       // bf16 residual stream
  u16*   qkv  = (u16*)  alloc((size_t)M_ * QKVN * 2);
  u16*   ob_  = (u16*)  alloc((size_t)M_ * H_ * 2);
  u16*   m1   = (u16*)  alloc((size_t)M_ * FF_ * 2);
  u16*   Pb   = (u16*)  alloc((size_t)4 * M_ * H_ * 2);   // bf16 split-K partials
  u16*   hT   = (u16*)  alloc((size_t)V_ * H_ * 2);
  u16*   qkvT = (u16*)  alloc((size_t)QKVN * H_ * 2);
  u16*   oT   = (u16*)  alloc((size_t)H_ * H_ * 2);
  u16*   w1Tb = (u16*)  alloc((size_t)2 * H_ * FF_ * 2);  // double-buffered
  u16*   w2Tb = (u16*)  alloc((size_t)2 * FF_ * H_ * 2);  // double-buffered
  float* bqkv = (float*)alloc((size_t)L_ * QKVN * 4);
  (void)in_sizes; (void)n_in; (void)out_size; (void)ws_size;

  auto w1T = [&](int l) { return w1Tb + (size_t)(l & 1) * H_ * FF_; };
  auto w2T = [&](int l) { return w2Tb + (size_t)(l & 1) * FF_ * H_; };

  // transposes(l0) first, then embed rows, then bias concat
  embed_concat_kernel<<<768 + M_ + L_, 256, 0, stream>>>(
      x, tok, pos, hb, bq, bk, bv, bqkv,
      Wq, Wk, Wv, Wo, W1, W2, qkvT, oT, w1T(0), w2T(0));

  for (int l = 0; l < L_; ++l) {
    // QKV: [2048,3072]
    gemm3<false, false, false, true><<<dim3(QKVN / 128, M_ / 128, 1), 256, 0, stream>>>(
        hb, qkvT, bqkv + (size_t)l * QKVN, nullptr, qkv, nullptr, QKVN, H_, H_);
    attn_kernel<<<dim3(T_ / 128, MB_ * NH_), 512, 0, stream>>>(qkv, ob_);
    // O-proj: split-K x4 -> 512 blocks, bf16 partials
    gemm3<true, false, false, false><<<dim3(H_ / 128, M_ / 128, 4), 256, 0, stream>>>(
        ob_, oT, nullptr, nullptr, nullptr, Pb, H_, H_, H_ / 4);
    ln2_kernel<<<M_, 256, 0, stream>>>(Pb, 4, bo + l * H_, g1 + l * H_, be1 + l * H_,
                                       nullptr, nullptr, hb);
    // transposes(l+1 or head) first, W1+GELU last
    if (l + 1 < L_) {
      int nl = l + 1;
      gemmW1_fused<<<768 + 512, 256, 0, stream>>>(
          hb, w1T(l), b1 + (size_t)l * FF_, m1,
          Wq + (size_t)nl * H_ * H_, Wk + (size_t)nl * H_ * H_,
          Wv + (size_t)nl * H_ * H_, Wo + (size_t)nl * H_ * H_,
          W1 + (size_t)nl * H_ * FF_, W2 + (size_t)nl * FF_ * H_,
          qkvT, oT, w1T(nl), w2T(nl), nullptr, nullptr);
    } else {
      gemmW1_fused<<<512 + 512, 256, 0, stream>>>(
          hb, w1T(l), b1 + (size_t)l * FF_, m1,
          nullptr, nullptr, nullptr, nullptr, nullptr, nullptr,
          nullptr, nullptr, nullptr, nullptr, hW, hT);
    }
    // W2: split-K x4 -> bf16 partials
    gemm3<true, false, false, false><<<dim3(H_ / 128, M_ / 128, 4), 256, 0, stream>>>(
        m1, w2T(l), nullptr, nullptr, nullptr, Pb, H_, FF_, FF_ / 4);
    if (l + 1 < L_) {
      ln2_kernel<<<M_, 256, 0, stream>>>(Pb, 4, b2 + l * H_, g2 + l * H_, be2 + l * H_,
                                         nullptr, nullptr, hb);
    } else {
      // fused: ln2 + final LayerNorm
      ln2_kernel<<<M_, 256, 0, stream>>>(Pb, 4, b2 + l * H_, g2 + l * H_, be2 + l * H_,
                                         gf, bef, hb);
    }
  }

  gemm3<false, false, true, false><<<dim3(V_ / 128, M_ / 128, 1), 256, 0, stream>>>(
      hb, hT, hbias, out, nullptr, nullptr, V_, H_, H_);
}

// Round 17
// 969.546 us; speedup vs baseline: 1.0301x; 1.0103x over previous
//
#include <hip/hip_runtime.h>
#include <hip/hip_bf16.h>

#define DEV __device__ __forceinline__

typedef unsigned short u16;
typedef __attribute__((ext_vector_type(8))) short bf16x8;
typedef __attribute__((ext_vector_type(4))) float f32x4;

static constexpr int MB_ = 2;
static constexpr int T_  = 1024;
static constexpr int H_  = 1024;
static constexpr int NH_ = 16;
static constexpr int L_  = 6;
static constexpr int V_  = 8192;
static constexpr int FF_ = 4096;
static constexpr int M_  = MB_ * T_;   // 2048 token rows
static constexpr int QKVN = 3 * H_;

DEV u16 f2bf(float x) {
  __hip_bfloat16 h = __float2bfloat16(x);
  return *reinterpret_cast<u16*>(&h);
}
DEV float bf2f(u16 v) {
  unsigned u = (unsigned)v << 16;
  float f;
  __builtin_memcpy(&f, &u, 4);
  return f;
}

// ---------------- transpose: 128x128 per block, double-buffered subtiles ------
DEV void transpose_tile128s(float (*Ts)[64][65], const float* __restrict__ W,
                            u16* __restrict__ WT, int R, int C, int bx, int by)
{
  const int t = threadIdx.x;
  const int lr = t >> 4;             // 0..15
  const int lcq = (t & 15) * 4;      // 0..60
  #pragma unroll
  for (int si = 0; si < 2; ++si) {
    const int r0 = by * 128 + si * 64;
    #pragma unroll
    for (int sj = 0; sj < 2; ++sj) {
      const int c0 = bx * 128 + sj * 64;
      #pragma unroll
      for (int it = 0; it < 4; ++it) {
        int r = it * 16 + lr;
        float4 v = *(const float4*)(W + (size_t)(r0 + r) * C + c0 + lcq);
        Ts[sj][r][lcq + 0] = v.x; Ts[sj][r][lcq + 1] = v.y;
        Ts[sj][r][lcq + 2] = v.z; Ts[sj][r][lcq + 3] = v.w;
      }
    }
    __syncthreads();
    #pragma unroll
    for (int sj = 0; sj < 2; ++sj) {
      const int c0 = bx * 128 + sj * 64;
      #pragma unroll
      for (int it = 0; it < 4; ++it) {
        int n = it * 16 + lr;
        ushort4 u = make_ushort4(f2bf(Ts[sj][lcq + 0][n]), f2bf(Ts[sj][lcq + 1][n]),
                                 f2bf(Ts[sj][lcq + 2][n]), f2bf(Ts[sj][lcq + 3][n]));
        *(ushort4*)(WT + (size_t)(c0 + n) * R + r0 + lcq) = u;
      }
    }
    __syncthreads();
  }
}

// 768 ids: Wq,Wk,Wv,Wo (4x64) + W1 (256) + W2 (256)
DEV void transpose_layer_body(float (*Ts)[64][65], int t,
    const float* Wq, const float* Wk, const float* Wv, const float* Wo,
    const float* W1, const float* W2,
    u16* qkvT, u16* oT, u16* w1T, u16* w2T)
{
  if (t < 256) {
    int m = t >> 6, idx = t & 63, bx = idx & 7, by = idx >> 3;
    const float* W = (m == 0) ? Wq : (m == 1) ? Wk : (m == 2) ? Wv : Wo;
    u16* WT = (m == 3) ? oT : qkvT + (size_t)m * H_ * H_;
    transpose_tile128s(Ts, W, WT, H_, H_, bx, by);
  } else if (t < 512) {
    int idx = t - 256;
    transpose_tile128s(Ts, W1, w1T, H_, FF_, idx & 31, idx >> 5);
  } else {
    int idx = t - 512;
    transpose_tile128s(Ts, W2, w2T, FF_, H_, idx & 7, idx >> 3);
  }
}

// ---------------- embedding + qkv-bias concat + layer-0 transpose (fused) -----
__global__ __launch_bounds__(256) void embed_concat_kernel(
    const int* __restrict__ x, const float* __restrict__ tok,
    const float* __restrict__ pos, u16* __restrict__ hb,
    const float* __restrict__ bq, const float* __restrict__ bk,
    const float* __restrict__ bv, float* __restrict__ outb,
    const float* Wq0, const float* Wk0, const float* Wv0, const float* Wo0,
    const float* W10, const float* W20,
    u16* qkvT, u16* oT, u16* w1T0, u16* w2T0)
{
  __shared__ float Ts[2][64][65];
  int i = blockIdx.x;
  if (i < 768) {
    transpose_layer_body(Ts, i, Wq0, Wk0, Wv0, Wo0, W10, W20,
                         qkvT, oT, w1T0, w2T0);
  } else if (i < 768 + M_) {
    int row = i - 768;
    int t = threadIdx.x;
    int id = x[row];
    int tt = row & (T_ - 1);
    float4 a = *(const float4*)(tok + (size_t)id * H_ + t * 4);
    float4 b = *(const float4*)(pos + (size_t)tt * H_ + t * 4);
    ushort4 u = make_ushort4(f2bf(a.x + b.x), f2bf(a.y + b.y),
                             f2bf(a.z + b.z), f2bf(a.w + b.w));
    *(ushort4*)(hb + (size_t)row * H_ + t * 4) = u;
  } else {
    int l = i - 768 - M_;
    for (int j = threadIdx.x; j < H_; j += 256) {
      outb[(size_t)l * QKVN + j]          = bq[(size_t)l * H_ + j];
      outb[(size_t)l * QKVN + H_ + j]     = bk[(size_t)l * H_ + j];
      outb[(size_t)l * QKVN + 2 * H_ + j] = bv[(size_t)l * H_ + j];
    }
  }
}

// ---------------- pipelined GEMM body (r8 schedule), templated BN -------------
// 4-buffer, BK=32, counted vmcnt, STG-early. 2-row-packed conflict-free LDS
// (r8-verified: SQ_LDS_BANK_CONFLICT=0). BN=128: 64KB LDS, 2 blk/CU.
// BN=64: 48KB LDS (3 blk/CU), B staged by waves 0..1 only -> per-wave counted
// waits 8/4 steady, 4/2 penultimate (barrier covers cross-wave visibility).

#define GLOAD_LDS16(g, l)                                              \
  __builtin_amdgcn_global_load_lds(                                    \
      (const __attribute__((address_space(1))) void*)(g),              \
      (__attribute__((address_space(3))) void*)(l), 16, 0, 0)

DEV void stage_t(const u16* __restrict__ G, int ldk, int r0g, int kofs,
                 u16* lds, int w, int lane)
{
  const int rl = ((lane >> 3) << 1) | ((lane >> 2) & 1);  // logical row in 16-group
  #pragma unroll
  for (int j = 0; j < 2; ++j) {
    const int row0 = w * 32 + j * 16;
    const int row = row0 + rl;
    const int c = (lane & 3) ^ (((row0 >> 1) + (lane >> 3)) & 3);
    const u16* g = G + (size_t)(r0g + row) * ldk + kofs + c * 8;
    GLOAD_LDS16(g, lds + row0 * 32);        // wave-uniform base, lane*16B auto
  }
}

DEV bf16x8 frag3(const u16* lds, int rr, int ch) {
  return *(const bf16x8*)(lds + (rr >> 1) * 64 + (rr & 1) * 32 +
                          ((ch ^ ((rr >> 1) & 3)) * 8));
}

template<int N>
DEV void wait_vm_barrier() {
  asm volatile("s_waitcnt vmcnt(%0)" :: "n"(N) : "memory");
  __builtin_amdgcn_s_barrier();
}

template<int NFN>
DEV void comp3(const u16* As, const u16* Bs, f32x4 (&acc)[4][NFN],
               int wr, int wc, int lc, int lg)
{
  bf16x8 af[4], bv[NFN];
  #pragma unroll
  for (int mi = 0; mi < 4; ++mi)
    af[mi] = frag3(As, wr * 64 + mi * 16 + lc, lg);
  #pragma unroll
  for (int ni = 0; ni < NFN; ++ni)
    bv[ni] = frag3(Bs, wc * (NFN * 16) + ni * 16 + lc, lg);
  #pragma unroll
  for (int mi = 0; mi < 4; ++mi)
    #pragma unroll
    for (int ni = 0; ni < NFN; ++ni)
      acc[mi][ni] = __builtin_amdgcn_mfma_f32_16x16x32_bf16(af[mi], bv[ni], acc[mi][ni], 0, 0, 0);
}

template<int BN, bool PARTIAL, bool DO_GELU, bool WF, bool WB>
DEV void gemm_body(u16* SMEM,
    const u16* __restrict__ A, const u16* __restrict__ BT,
    const float* __restrict__ bias, float* __restrict__ Cf,
    u16* __restrict__ Cb, u16* __restrict__ Pb,
    int N, int K, int Ksub, int lid, int nwgx, int nwgy, int zid)
{
  constexpr int NFN = BN / 32;               // frags/wave in N (wave = BN/2 cols)
  constexpr int BW  = BN >> 5;               // waves staging B (32 rows each)
  constexpr int BSTEP = BN * 32;             // u16 per B buffer

  const int tid = threadIdx.x;
  const int lane = tid & 63, w = tid >> 6;
  const int wr = w >> 1, wc = w & 1;
  const int lc = lane & 15, lg = lane >> 4;
  const bool fullld = (BN == 128) || (w < BW);

  // bijective XCD swizzle, m FASTEST within an XCD (B-panel reuse per XCD)
  const int nwg = nwgx * nwgy;
  const int q8 = nwg >> 3, r8s = nwg & 7;
  const int xcd = lid & 7, ord = lid >> 3;
  const int sid = (xcd < r8s ? xcd * (q8 + 1) : r8s * (q8 + 1) + (xcd - r8s) * q8) + ord;
  const int m0 = (sid % nwgy) * 128, n0 = (sid / nwgy) * BN;

  const int kb = zid * Ksub;
  const int NT = Ksub >> 5;

  f32x4 acc[4][NFN];
  #pragma unroll
  for (int i = 0; i < 4; ++i)
    #pragma unroll
    for (int j = 0; j < NFN; ++j) {
      f32x4 z = {0.f, 0.f, 0.f, 0.f};
      acc[i][j] = z;
    }

  auto STG = [&](int t, int b) {
    stage_t(A, K, m0, kb + t * 32, SMEM + b * 4096, w, lane);
    if (BN == 128 || w < BW)
      stage_t(BT, K, n0, kb + t * 32, SMEM + 16384 + b * BSTEP, w, lane);
  };

  STG(0, 0);
  STG(1, 1);
  int t = 0;
  for (; t < NT - 2; ++t) {
    STG(t + 2, (t + 2) & 3);
    if (fullld) wait_vm_barrier<8>(); else wait_vm_barrier<4>();
    comp3<NFN>(SMEM + (t & 3) * 4096, SMEM + 16384 + (t & 3) * BSTEP, acc, wr, wc, lc, lg);
  }
  if (fullld) wait_vm_barrier<4>(); else wait_vm_barrier<2>();
  comp3<NFN>(SMEM + (t & 3) * 4096, SMEM + 16384 + (t & 3) * BSTEP, acc, wr, wc, lc, lg);
  ++t;
  wait_vm_barrier<0>();
  comp3<NFN>(SMEM + (t & 3) * 4096, SMEM + 16384 + (t & 3) * BSTEP, acc, wr, wc, lc, lg);

  const size_t zofs = (size_t)zid * M_ * N;
  #pragma unroll
  for (int mi = 0; mi < 4; ++mi) {
    #pragma unroll
    for (int ni = 0; ni < NFN; ++ni) {
      int gn = n0 + wc * (NFN * 16) + ni * 16 + lc;
      float bvv = PARTIAL ? 0.f : bias[gn];
      #pragma unroll
      for (int r = 0; r < 4; ++r) {
        int gm = m0 + wr * 64 + mi * 16 + lg * 4 + r;
        float v = acc[mi][ni][r];
        if (PARTIAL) {
          Pb[zofs + (size_t)gm * N + gn] = f2bf(v);   // bf16 partials
        } else {
          v += bvv;
          if (DO_GELU) v = 0.5f * v * (1.f + erff(v * 0.70710678118654752f));
          if (WF) Cf[(size_t)gm * N + gn] = v;
          if (WB) Cb[(size_t)gm * N + gn] = f2bf(v);
        }
      }
    }
  }
}

template<int BN, bool PARTIAL, bool DO_GELU, bool WF, bool WB>
__global__ __launch_bounds__(256, 2) void gemm3(
    const u16* __restrict__ A, const u16* __restrict__ BT,
    const float* __restrict__ bias, float* __restrict__ Cf,
    u16* __restrict__ Cb, u16* __restrict__ Pb, int N, int K, int Ksub)
{
  __shared__ __align__(16) u16 SMEM[16384 + BN * 32 * 4];
  gemm_body<BN, PARTIAL, DO_GELU, WF, WB>(SMEM, A, BT, bias, Cf, Cb, Pb, N, K, Ksub,
      blockIdx.y * gridDim.x + blockIdx.x, gridDim.x, gridDim.y, blockIdx.z);
}

// transposes FIRST (narrow latency-bound), W1 GEMM last (wide tail).
__global__ __launch_bounds__(256, 2) void gemmW1_fused(
    const u16* __restrict__ A, const u16* __restrict__ w1T,
    const float* __restrict__ bias, u16* __restrict__ m1,
    const float* nWq, const float* nWk, const float* nWv, const float* nWo,
    const float* nW1, const float* nW2,
    u16* nqkvT, u16* noT, u16* nw1T, u16* nw2T,
    const float* hW, u16* hT)
{
  __shared__ __align__(16) u16 SMEM[32768];
  const int id = blockIdx.x;
  const int ntr = nWq ? 768 : 512;
  if (id < ntr) {
    float (*Ts)[64][65] = (float(*)[64][65])SMEM;   // 33 KB of the 64 KB union
    if (nWq) {
      transpose_layer_body(Ts, id, nWq, nWk, nWv, nWo, nW1, nW2,
                           nqkvT, noT, nw1T, nw2T);
    } else {
      transpose_tile128s(Ts, hW, hT, H_, V_, id & 63, id >> 6);  // 512 head tiles
    }
  } else {
    gemm_body<128, false, true, false, true>(SMEM, A, w1T, bias, nullptr, m1, nullptr,
                                             FF_, H_, H_, id - ntr, 32, 16, 0);
  }
}

// ---------------- split-K reduce (bf16 partials) + bias + residual + LN -------
__global__ __launch_bounds__(256) void ln2_kernel(
    const u16* __restrict__ Pb, int S,
    const float* __restrict__ bias,
    const float* __restrict__ g, const float* __restrict__ be,
    const float* __restrict__ gf, const float* __restrict__ bef,
    u16* __restrict__ hb)
{
  __shared__ float red[8];
  int row = blockIdx.x, t = threadIdx.x;
  int lane = t & 63, w = t >> 6;
  ushort4 hv = *(const ushort4*)(hb + (size_t)row * H_ + t * 4);
  float4 bb = *(const float4*)(bias + t * 4);
  float4 v = make_float4(bf2f(hv.x) + bb.x, bf2f(hv.y) + bb.y,
                         bf2f(hv.z) + bb.z, bf2f(hv.w) + bb.w);
  for (int s0 = 0; s0 < S; ++s0) {
    ushort4 p = *(const ushort4*)(Pb + (size_t)s0 * M_ * H_ + (size_t)row * H_ + t * 4);
    v.x += bf2f(p.x); v.y += bf2f(p.y); v.z += bf2f(p.z); v.w += bf2f(p.w);
  }
  float s = v.x + v.y + v.z + v.w;
  float q = v.x * v.x + v.y * v.y + v.z * v.z + v.w * v.w;
  #pragma unroll
  for (int o = 1; o < 64; o <<= 1) { s += __shfl_xor(s, o); q += __shfl_xor(q, o); }
  if (lane == 0) { red[w] = s; red[4 + w] = q; }
  __syncthreads();
  float S1 = red[0] + red[1] + red[2] + red[3];
  float Q1 = red[4] + red[5] + red[6] + red[7];
  float mu  = S1 * (1.f / H_);
  float var = Q1 * (1.f / H_) - mu * mu;
  float inv = rsqrtf(var + 1e-5f);
  float4 gv = *(const float4*)(g  + t * 4);
  float4 bv = *(const float4*)(be + t * 4);
  float o0 = (v.x - mu) * inv * gv.x + bv.x;
  float o1 = (v.y - mu) * inv * gv.y + bv.y;
  float o2 = (v.z - mu) * inv * gv.z + bv.z;
  float o3 = (v.w - mu) * inv * gv.w + bv.w;
  if (gf != nullptr) {
    float s2 = o0 + o1 + o2 + o3;
    float q2 = o0 * o0 + o1 * o1 + o2 * o2 + o3 * o3;
    #pragma unroll
    for (int o = 1; o < 64; o <<= 1) { s2 += __shfl_xor(s2, o); q2 += __shfl_xor(q2, o); }
    __syncthreads();                       // WAR on red
    if (lane == 0) { red[w] = s2; red[4 + w] = q2; }
    __syncthreads();
    float S2 = red[0] + red[1] + red[2] + red[3];
    float Q2 = red[4] + red[5] + red[6] + red[7];
    float mu2  = S2 * (1.f / H_);
    float var2 = Q2 * (1.f / H_) - mu2 * mu2;
    float inv2 = rsqrtf(var2 + 1e-5f);
    float4 gv2 = *(const float4*)(gf  + t * 4);
    float4 bv2 = *(const float4*)(bef + t * 4);
    o0 = (o0 - mu2) * inv2 * gv2.x + bv2.x;
    o1 = (o1 - mu2) * inv2 * gv2.y + bv2.y;
    o2 = (o2 - mu2) * inv2 * gv2.z + bv2.z;
    o3 = (o3 - mu2) * inv2 * gv2.w + bv2.w;
  }
  ushort4 u = make_ushort4(f2bf(o0), f2bf(o1), f2bf(o2), f2bf(o3));
  *(ushort4*)(hb + (size_t)row * H_ + t * 4) = u;
}

// ---------------- flash attention (causal), QBLK=128, 8 waves ----------------
__global__ __launch_bounds__(512) void attn_kernel(
    const u16* __restrict__ qkv, u16* __restrict__ Og)
{
  __shared__ __align__(16) u16 Ks[2][64][72];
  __shared__ __align__(16) u16 Vs[2][64][72];      // transposed: [d][key]
  __shared__ __align__(16) u16 QPs[8][16][72];     // Q stage (prologue) / P bounce

  const int qb = gridDim.x - 1 - blockIdx.x;       // long blocks first
  const int bh = blockIdx.y;
  const int b = bh >> 4, hh = bh & 15;
  const int q0 = qb * 128;
  const size_t base  = ((size_t)b * T_) * QKVN + (size_t)hh * 64;
  const size_t baseO = ((size_t)b * T_) * H_ + (size_t)hh * 64;

  const int tid = threadIdx.x;
  const int lane = tid & 63, w = tid >> 6;         // 8 waves
  const int lc = lane & 15, lg = lane >> 4;

  const int rk = tid >> 3, dk = (tid & 7) << 3;    // K: 64 rows x 8 chunks
  const int vk = tid & 63, vd = (tid >> 6) << 3;   // V: 64 rows x 8 d-chunks
  const int rq = tid >> 2, cq = (tid & 3) << 4;    // Q: 128 rows x 2 chunks

  bf16x8 kr, vr;
  kr = *(const bf16x8*)(qkv + base + H_ + (size_t)rk * QKVN + dk);
  vr = *(const bf16x8*)(qkv + base + 2 * H_ + (size_t)vk * QKVN + vd);
  *(bf16x8*)&QPs[rq >> 4][rq & 15][cq] =
      *(const bf16x8*)(qkv + base + (size_t)(q0 + rq) * QKVN + cq);
  *(bf16x8*)&QPs[rq >> 4][rq & 15][cq + 8] =
      *(const bf16x8*)(qkv + base + (size_t)(q0 + rq) * QKVN + cq + 8);
  *(bf16x8*)&Ks[0][rk][dk] = kr;
  #pragma unroll
  for (int j = 0; j < 8; ++j) Vs[0][vd + j][vk] = ((const u16*)&vr)[j];
  __syncthreads();
  bf16x8 aq0 = *(const bf16x8*)&QPs[w][lc][lg * 8];
  bf16x8 aq1 = *(const bf16x8*)&QPs[w][lc][32 + lg * 8];

  float m_r[4], l_r[4];
  f32x4 oa[4];
  #pragma unroll
  for (int i = 0; i < 4; ++i) {
    m_r[i] = -1e30f; l_r[i] = 0.f;
    f32x4 z = {0.f, 0.f, 0.f, 0.f};
    oa[i] = z;
  }
  const float sc2 = 0.125f * 1.4426950408889634f;
  const int NT = 2 * qb + 2;
  const int rmin = q0 + w * 16;                    // wave's first q-row

  for (int kv = 0; kv < NT; ++kv) {
    const int cur = kv & 1, nxt = cur ^ 1;
    if (kv + 1 < NT) {
      kr = *(const bf16x8*)(qkv + base + H_ + (size_t)((kv + 1) * 64 + rk) * QKVN + dk);
      vr = *(const bf16x8*)(qkv + base + 2 * H_ + (size_t)((kv + 1) * 64 + vk) * QKVN + vd);
    }

    const bool live = (kv * 64 <= rmin + 15);      // else tile fully masked
    if (live) {
      const bool partial = (kv * 64 + 63 > rmin);
      f32x4 sfr[4];
      #pragma unroll
      for (int ni = 0; ni < 4; ++ni) { f32x4 z = {0.f,0.f,0.f,0.f}; sfr[ni] = z; }
      __builtin_amdgcn_s_setprio(1);
      #pragma unroll
      for (int ni = 0; ni < 4; ++ni) {
        bf16x8 bk0 = *(const bf16x8*)&Ks[cur][ni * 16 + lc][lg * 8];
        bf16x8 bk1 = *(const bf16x8*)&Ks[cur][ni * 16 + lc][32 + lg * 8];
        sfr[ni] = __builtin_amdgcn_mfma_f32_16x16x32_bf16(aq0, bk0, sfr[ni], 0, 0, 0);
        sfr[ni] = __builtin_amdgcn_mfma_f32_16x16x32_bf16(aq1, bk1, sfr[ni], 0, 0, 0);
      }
      __builtin_amdgcn_s_setprio(0);
      if (partial) {
        #pragma unroll
        for (int ni = 0; ni < 4; ++ni)
          #pragma unroll
          for (int r = 0; r < 4; ++r)
            if (kv * 64 + ni * 16 + lc > rmin + lg * 4 + r) sfr[ni][r] = -1e30f;
      }
      #pragma unroll
      for (int r = 0; r < 4; ++r) {
        float pm = fmaxf(fmaxf(sfr[0][r], sfr[1][r]), fmaxf(sfr[2][r], sfr[3][r]));
        pm = fmaxf(pm, __shfl_xor(pm, 1));
        pm = fmaxf(pm, __shfl_xor(pm, 2));
        pm = fmaxf(pm, __shfl_xor(pm, 4));
        pm = fmaxf(pm, __shfl_xor(pm, 8));
        float mn = fmaxf(m_r[r], pm);
        float al = exp2f(sc2 * (m_r[r] - mn));
        m_r[r] = mn; l_r[r] *= al;
        #pragma unroll
        for (int f = 0; f < 4; ++f) oa[f][r] *= al;
        float rs = 0.f;
        #pragma unroll
        for (int ni = 0; ni < 4; ++ni) {
          float p = exp2f(sc2 * (sfr[ni][r] - mn));
          sfr[ni][r] = p; rs += p;
        }
        rs += __shfl_xor(rs, 1); rs += __shfl_xor(rs, 2);
        rs += __shfl_xor(rs, 4); rs += __shfl_xor(rs, 8);
        l_r[r] += rs;
      }
      #pragma unroll
      for (int ni = 0; ni < 4; ++ni)
        #pragma unroll
        for (int r = 0; r < 4; ++r)
          QPs[w][lg * 4 + r][ni * 16 + lc] = f2bf(sfr[ni][r]);
      bf16x8 ap0 = *(const bf16x8*)&QPs[w][lc][lg * 8];
      bf16x8 ap1 = *(const bf16x8*)&QPs[w][lc][32 + lg * 8];
      __builtin_amdgcn_s_setprio(1);
      #pragma unroll
      for (int f = 0; f < 4; ++f) {
        bf16x8 bv0 = *(const bf16x8*)&Vs[cur][f * 16 + lc][lg * 8];
        bf16x8 bv1 = *(const bf16x8*)&Vs[cur][f * 16 + lc][32 + lg * 8];
        oa[f] = __builtin_amdgcn_mfma_f32_16x16x32_bf16(ap0, bv0, oa[f], 0, 0, 0);
        oa[f] = __builtin_amdgcn_mfma_f32_16x16x32_bf16(ap1, bv1, oa[f], 0, 0, 0);
      }
      __builtin_amdgcn_s_setprio(0);
    }

    if (kv + 1 < NT) {
      *(bf16x8*)&Ks[nxt][rk][dk] = kr;
      #pragma unroll
      for (int j = 0; j < 8; ++j) Vs[nxt][vd + j][vk] = ((const u16*)&vr)[j];
      __syncthreads();
    }
  }

  #pragma unroll
  for (int r = 0; r < 4; ++r) {
    float inv = 1.f / l_r[r];
    int grow = q0 + w * 16 + lg * 4 + r;
    #pragma unroll
    for (int f = 0; f < 4; ++f)
      Og[baseO + (size_t)grow * H_ + f * 16 + lc] = f2bf(oa[f][r] * inv);
  }
}

// ---------------- host ----------------
extern "C" void kernel_launch(void* const* d_in, const int* in_sizes, int n_in,
                              void* d_out, int out_size, void* d_ws, size_t ws_size,
                              hipStream_t stream)
{
  const int*   x    = (const int*)  d_in[0];
  const float* tok  = (const float*)d_in[1];
  const float* pos  = (const float*)d_in[2];
  const float* Wq   = (const float*)d_in[3];
  const float* bq   = (const float*)d_in[4];
  const float* Wk   = (const float*)d_in[5];
  const float* bk   = (const float*)d_in[6];
  const float* Wv   = (const float*)d_in[7];
  const float* bv   = (const float*)d_in[8];
  const float* Wo   = (const float*)d_in[9];
  const float* bo   = (const float*)d_in[10];
  const float* W1   = (const float*)d_in[11];
  const float* b1   = (const float*)d_in[12];
  const float* W2   = (const float*)d_in[13];
  const float* b2   = (const float*)d_in[14];
  const float* g1   = (const float*)d_in[15];
  const float* be1  = (const float*)d_in[16];
  const float* g2   = (const float*)d_in[17];
  const float* be2  = (const float*)d_in[18];
  const float* gf   = (const float*)d_in[19];
  const float* bef  = (const float*)d_in[20];
  const float* hW   = (const float*)d_in[21];
  const float* hbias= (const float*)d_in[22];
  float* out = (float*)d_out;

  char* wsp = (char*)d_ws;
  size_t off = 0;
  auto alloc = [&](size_t bytes) -> void* {
    void* p = wsp + off;
    off += (bytes + 255) & ~(size_t)255;
    return p;
  };
  u16*   hb   = (u16*)  alloc((size_t)M_ * H_ * 2);       // bf16 residual stream
  u16*   qkv  = (u16*)  alloc((size_t)M_ * QKVN * 2);
  u16*   ob_  = (u16*)  alloc((size_t)M_ * H_ * 2);
  u16*   m1   = (u16*)  alloc((size_t)M_ * FF_ * 2);
  u16*   Pb   = (u16*)  alloc((size_t)4 * M_ * H_ * 2);   // bf16 split-K partials
  u16*   hT   = (u16*)  alloc((size_t)V_ * H_ * 2);
  u16*   qkvT = (u16*)  alloc((size_t)QKVN * H_ * 2);
  u16*   oT   = (u16*)  alloc((size_t)H_ * H_ * 2);
  u16*   w1Tb = (u16*)  alloc((size_t)2 * H_ * FF_ * 2);  // double-buffered
  u16*   w2Tb = (u16*)  alloc((size_t)2 * FF_ * H_ * 2);  // double-buffered
  float* bqkv = (float*)alloc((size_t)L_ * QKVN * 4);
  (void)in_sizes; (void)n_in; (void)out_size; (void)ws_size;

  auto w1T = [&](int l) { return w1Tb + (size_t)(l & 1) * H_ * FF_; };
  auto w2T = [&](int l) { return w2Tb + (size_t)(l & 1) * FF_ * H_; };

  // transposes(l0) first, then embed rows, then bias concat
  embed_concat_kernel<<<768 + M_ + L_, 256, 0, stream>>>(
      x, tok, pos, hb, bq, bk, bv, bqkv,
      Wq, Wk, Wv, Wo, W1, W2, qkvT, oT, w1T(0), w2T(0));

  for (int l = 0; l < L_; ++l) {
    // QKV: [2048,3072]
    gemm3<128, false, false, false, true><<<dim3(QKVN / 128, M_ / 128, 1), 256, 0, stream>>>(
        hb, qkvT, bqkv + (size_t)l * QKVN, nullptr, qkv, nullptr, QKVN, H_, H_);
    attn_kernel<<<dim3(T_ / 128, MB_ * NH_), 512, 0, stream>>>(qkv, ob_);
    // O-proj: BN=64, split-K x2 -> 16x16x2 = 512 blocks, NT=16, S=2 partials
    gemm3<64, true, false, false, false><<<dim3(H_ / 64, M_ / 128, 2), 256, 0, stream>>>(
        ob_, oT, nullptr, nullptr, nullptr, Pb, H_, H_, H_ / 2);
    ln2_kernel<<<M_, 256, 0, stream>>>(Pb, 2, bo + l * H_, g1 + l * H_, be1 + l * H_,
                                       nullptr, nullptr, hb);
    // transposes(l+1 or head) first, W1+GELU last
    if (l + 1 < L_) {
      int nl = l + 1;
      gemmW1_fused<<<768 + 512, 256, 0, stream>>>(
          hb, w1T(l), b1 + (size_t)l * FF_, m1,
          Wq + (size_t)nl * H_ * H_, Wk + (size_t)nl * H_ * H_,
          Wv + (size_t)nl * H_ * H_, Wo + (size_t)nl * H_ * H_,
          W1 + (size_t)nl * H_ * FF_, W2 + (size_t)nl * FF_ * H_,
          qkvT, oT, w1T(nl), w2T(nl), nullptr, nullptr);
    } else {
      gemmW1_fused<<<512 + 512, 256, 0, stream>>>(
          hb, w1T(l), b1 + (size_t)l * FF_, m1,
          nullptr, nullptr, nullptr, nullptr, nullptr, nullptr,
          nullptr, nullptr, nullptr, nullptr, hW, hT);
    }
    // W2: BN=128, split-K x4 -> 512 blocks, bf16 partials
    gemm3<128, true, false, false, false><<<dim3(H_ / 128, M_ / 128, 4), 256, 0, stream>>>(
        m1, w2T(l), nullptr, nullptr, nullptr, Pb, H_, FF_, FF_ / 4);
    if (l + 1 < L_) {
      ln2_kernel<<<M_, 256, 0, stream>>>(Pb, 4, b2 + l * H_, g2 + l * H_, be2 + l * H_,
                                         nullptr, nullptr, hb);
    } else {
      // fused: ln2 + final LayerNorm
      ln2_kernel<<<M_, 256, 0, stream>>>(Pb, 4, b2 + l * H_, g2 + l * H_, be2 + l * H_,
                                         gf, bef, hb);
    }
  }

  gemm3<128, false, false, true, false><<<dim3(V_ / 128, M_ / 128, 1), 256, 0, stream>>>(
      hb, hT, hbias, out, nullptr, nullptr, V_, H_, H_);
}